// Round 6
// baseline (331.106 us; speedup 1.0000x reference)
//
#include <hip/hip_runtime.h>
#include <hip/hip_bf16.h>

#define D      128
#define LG     8
#define CHUNK  256   // (1 << LG)

typedef __attribute__((ext_vector_type(8))) short          short8;
typedef __attribute__((ext_vector_type(8))) unsigned short ushort8;
typedef __attribute__((ext_vector_type(4))) float          floatx4;

__device__ inline float b2f(unsigned short u) {
    return __uint_as_float(((unsigned)u) << 16);
}
__device__ inline short f2bf(float f) {
    __hip_bfloat16 h = __float2bfloat16(f);
    unsigned short u;
    __builtin_memcpy(&u, &h, 2);
    return (short)u;
}

__global__ void init_out_kernel(float* out, int out_size) {
    int t = threadIdx.x;
    if (t < out_size) out[t] = -INFINITY;
}

// Pass 1: single gather pass. Chunk-LOCAL inclusive cumsum of embedding rows,
// stored bf16; chunk totals to sumE (fp32).
__global__ void local_scan_kernel(const int* __restrict__ tokens,
                                  const float* __restrict__ emb,
                                  unsigned short* __restrict__ S,
                                  float* __restrict__ sumE, int n) {
    __shared__ int toks[CHUNK];
    int c  = blockIdx.x;
    int i0 = c << LG;
    int cnt = min(CHUNK, n - i0);
    for (int t = threadIdx.x; t < cnt; t += 128) toks[t] = tokens[i0 + t];
    __syncthreads();
    int d = threadIdx.x;
    float run = 0.f;
    #pragma unroll 8
    for (int j = 0; j < cnt; ++j) {
        run += emb[(size_t)toks[j] * D + d];
        S[(size_t)(i0 + j) * D + d] = (unsigned short)f2bf(run);
    }
    sumE[(size_t)c * D + d] = run;
}

// Pass 2: in-place exclusive scan of chunk totals (one wave per dim).
__global__ void scan_kernel(float* sumE, int C) {
    int d    = blockIdx.x;     // 0..127
    int lane = threadIdx.x;    // 0..63
    float carry = 0.f;
    for (int c0 = 0; c0 < C; c0 += 64) {
        int c = c0 + lane;
        float v = (c < C) ? sumE[(size_t)c * D + d] : 0.f;
        float incl = v;
        #pragma unroll
        for (int off = 1; off < 64; off <<= 1) {
            float t = __shfl_up(incl, off);
            if (lane >= off) incl += t;
        }
        if (c < C) sumE[(size_t)c * D + d] = carry + incl - v;  // exclusive
        carry += __shfl(incl, 63);
    }
}

__device__ inline void atomicMaxF(float* addr, float v) {
    if (v >= 0.f) atomicMax((int*)addr, __float_as_int(v));
    else          atomicMin((unsigned int*)addr, __float_as_uint(v));
}

// Pass 3: block = one 256-node chunk. Stage chunk's S rows in LDS (swizzled);
// h = W*S[e] - W*S[prev] + cnt*b via dual-accumulator MFMA (linearity — no
// per-element converts on the fast path). Cross-chunk e: global S row +
// prefE[ce]-prefE[cb] folded in bf16. Wave-pair scheme: tw half of W^T in
// registers (64 VGPR), pair shares node tiles.
__global__ __launch_bounds__(256, 2) void max_pass_kernel(
        const int* __restrict__ ends, const unsigned short* __restrict__ S,
        const float* __restrict__ prefE, const float* __restrict__ W,
        const float* __restrict__ bvec, float* __restrict__ out, int n) {
    __shared__ ushort8 Sl[257 * 16];   // 257 rows x 16 granules of 16B (swizzled)
    __shared__ int   s_end[CHUNK];
    __shared__ float red[4][4][16];
    int tid = threadIdx.x;
    int cb  = blockIdx.x;
    int i0  = cb << LG;
    int cnt = min(CHUNK, n - i0);

    // Stage ends (clamped identity for padding lanes).
    for (int t = tid; t < CHUNK; t += 256)
        s_end[t] = (i0 + t < n) ? ends[i0 + t] : (i0 + t);
    // Stage this chunk's S rows, XOR-swizzled on the 16B granule.
    const ushort8* gsrc = (const ushort8*)(S + (size_t)i0 * D);
    int units = cnt * 16;
    for (int u = tid; u < units; u += 256) {
        int r = u >> 4, q = u & 15;
        Sl[(r << 4) | (q ^ (r & 7))] = gsrc[u];
    }
    ushort8 z = {0, 0, 0, 0, 0, 0, 0, 0};
    for (int u = units + tid; u < 257 * 16; u += 256) {
        int r = u >> 4, q = u & 15;
        Sl[(r << 4) | (q ^ (r & 7))] = z;   // pad rows + zero row (r=256)
    }

    int lane = tid & 63, wid = tid >> 6;
    int c  = lane & 15;   // node-in-tile / C-col index
    int kg = lane >> 4;   // k-subgroup 0..3
    int tw   = wid & 1;   // which half of the 8 output-tiles
    int pair = wid >> 1;  // 0..1

    // Preload this wave's half of W (bf16 fragments) and bias slice.
    short8 Wf[4][4];
    float  bc[4];
    #pragma unroll
    for (int tl = 0; tl < 4; ++tl) {
        int tg = tw * 4 + tl;
        const float* wr = W + (size_t)(tg * 16 + c) * D + kg * 8;
        bc[tl] = bvec[tg * 16 + c];
        #pragma unroll
        for (int kk = 0; kk < 4; ++kk) {
            floatx4 f0 = *(const floatx4*)(wr + kk * 32);
            floatx4 f1 = *(const floatx4*)(wr + kk * 32 + 4);
            short8 w;
            #pragma unroll
            for (int j = 0; j < 4; ++j) { w[j] = f2bf(f0[j]); w[j + 4] = f2bf(f1[j]); }
            Wf[tl][kk] = w;
        }
    }
    float mx[4];
    #pragma unroll
    for (int tl = 0; tl < 4; ++tl) mx[tl] = -INFINITY;

    __syncthreads();

    int tiles = (cnt + 15) >> 4;
    int Tend  = min(pair * 8 + 8, tiles);
    for (int T = pair * 8; T < Tend; ++T) {
        int j    = (T << 4) + c;      // local node index (< 256)
        int node = i0 + j;
        bool vr  = node < n;
        int e    = s_end[j];
        int eloc = e - i0;            // >= j for valid nodes
        bool cross = vr && (eloc >= CHUNK);
        int re = cross ? j : eloc;    // LDS row for e (dummy j when cross)
        int rp = (j == 0) ? 256 : (j - 1);   // zero row for chunk head

        short8 Ae[4], Ap[4];
        #pragma unroll
        for (int kk = 0; kk < 4; ++kk) {
            ushort8 ve = Sl[(re << 4) | ((kk * 4 + kg) ^ (re & 7))];
            ushort8 vp = Sl[(rp << 4) | ((kk * 4 + kg) ^ (rp & 7))];
            __builtin_memcpy(&Ae[kk], &ve, 16);
            __builtin_memcpy(&Ap[kk], &vp, 16);
        }
        if (cross) {
            int ce = e >> LG;
            const ushort8* ge = (const ushort8*)(S + (size_t)e * D);
            const float* qe = prefE + (size_t)ce * D + kg * 8;
            const float* qc = prefE + (size_t)cb * D + kg * 8;
            #pragma unroll
            for (int kk = 0; kk < 4; ++kk) {
                ushort8 se = ge[kk * 4 + kg];
                floatx4 qe0 = *(const floatx4*)(qe + kk * 32);
                floatx4 qe1 = *(const floatx4*)(qe + kk * 32 + 4);
                floatx4 qc0 = *(const floatx4*)(qc + kk * 32);
                floatx4 qc1 = *(const floatx4*)(qc + kk * 32 + 4);
                short8 a;
                #pragma unroll
                for (int jj = 0; jj < 4; ++jj) {
                    a[jj]     = f2bf(b2f(se[jj])     + qe0[jj] - qc0[jj]);
                    a[jj + 4] = f2bf(b2f(se[jj + 4]) + qe1[jj] - qc1[jj]);
                }
                Ae[kk] = a;
            }
        }
        floatx4 cnt4;
        #pragma unroll
        for (int i = 0; i < 4; ++i) {
            int nd = i0 + (T << 4) + kg * 4 + i;
            float ee = (float)__shfl(e, kg * 4 + i);
            cnt4[i] = (nd < n) ? (ee - (float)nd + 1.f) : 0.f;
        }
        #pragma unroll
        for (int tl = 0; tl < 4; ++tl) {
            floatx4 ae = {0.f, 0.f, 0.f, 0.f};
            floatx4 ap = {0.f, 0.f, 0.f, 0.f};
            ae = __builtin_amdgcn_mfma_f32_16x16x32_bf16(Ae[0], Wf[tl][0], ae, 0, 0, 0);
            ae = __builtin_amdgcn_mfma_f32_16x16x32_bf16(Ae[1], Wf[tl][1], ae, 0, 0, 0);
            ae = __builtin_amdgcn_mfma_f32_16x16x32_bf16(Ae[2], Wf[tl][2], ae, 0, 0, 0);
            ae = __builtin_amdgcn_mfma_f32_16x16x32_bf16(Ae[3], Wf[tl][3], ae, 0, 0, 0);
            ap = __builtin_amdgcn_mfma_f32_16x16x32_bf16(Ap[0], Wf[tl][0], ap, 0, 0, 0);
            ap = __builtin_amdgcn_mfma_f32_16x16x32_bf16(Ap[1], Wf[tl][1], ap, 0, 0, 0);
            ap = __builtin_amdgcn_mfma_f32_16x16x32_bf16(Ap[2], Wf[tl][2], ap, 0, 0, 0);
            ap = __builtin_amdgcn_mfma_f32_16x16x32_bf16(Ap[3], Wf[tl][3], ap, 0, 0, 0);
            #pragma unroll
            for (int i = 0; i < 4; ++i) {
                int nd = i0 + (T << 4) + kg * 4 + i;
                float h = (ae[i] - ap[i]) + cnt4[i] * bc[tl];
                if (nd < n) mx[tl] = fmaxf(mx[tl], h);
            }
        }
    }
    // Reduce across the 4 k-subgroups (they hold the same d = tg*16+c).
    #pragma unroll
    for (int tl = 0; tl < 4; ++tl) {
        float v = mx[tl];
        v = fmaxf(v, __shfl_xor(v, 16));
        v = fmaxf(v, __shfl_xor(v, 32));
        mx[tl] = v;
    }
    if (kg == 0) {
        #pragma unroll
        for (int tl = 0; tl < 4; ++tl) red[wid][tl][c] = mx[tl];
    }
    __syncthreads();
    if (tid < 128) {
        // tid = twf*64 + tl*16 + cc ; combine wids {twf, twf+2} (same tw)
        int twf = tid >> 6;
        int tl  = (tid >> 4) & 3;
        int cc  = tid & 15;
        float v = fmaxf(red[twf][tl][cc], red[twf + 2][tl][cc]);
        atomicMaxF(&out[(twf * 4 + tl) * 16 + cc], v);
    }
}

extern "C" void kernel_launch(void* const* d_in, const int* in_sizes, int n_in,
                              void* d_out, int out_size, void* d_ws, size_t ws_size,
                              hipStream_t stream) {
    const int*   tokens = (const int*)d_in[0];
    const int*   ends   = (const int*)d_in[1];
    const float* emb    = (const float*)d_in[2];
    const float* W      = (const float*)d_in[3];
    const float* bvec   = (const float*)d_in[4];
    float* out = (float*)d_out;
    int n = in_sizes[0];
    int C = (n + CHUNK - 1) >> LG;

    unsigned short* S    = (unsigned short*)d_ws;          // n*128 bf16 = 256 MB
    float*          sumE = (float*)(S + (size_t)n * D);    // C*128 fp32 (scanned in place)
    // total = n*256 + C*512 bytes ≈ 258.0 MB for n=1e6

    init_out_kernel<<<1, 128, 0, stream>>>(out, out_size);
    local_scan_kernel<<<C, 128, 0, stream>>>(tokens, emb, S, sumE, n);
    scan_kernel<<<128, 64, 0, stream>>>(sumE, C);
    max_pass_kernel<<<C, 256, 0, stream>>>(ends, S, sumE, W, bvec, out, n);
}